// Round 16
// baseline (275.777 us; speedup 1.0000x reference)
//
#include <hip/hip_runtime.h>

#define NODES   50000
#define EDGES   800000
#define GRAPHS  500
#define HID     128
#define OUTC    10
#define NLAYERS 3
#define ELLCAP  64

typedef __bf16 bf16x8 __attribute__((ext_vector_type(8)));
typedef float  f32x4  __attribute__((ext_vector_type(4)));

__device__ __forceinline__ unsigned short f2bf(float f){
    unsigned u = __float_as_uint(f);
    u = (u + 0x7fffu + ((u >> 16) & 1u)) >> 16;
    return (unsigned short)u;
}
__device__ __forceinline__ float bf2f(unsigned short h){
    return __uint_as_float(((unsigned)h) << 16);
}

#define FGRPS  8                                // XCD groups
#define GSZ    (NODES / FGRPS)                  // 6250 nodes per group
#define GCAP   131072                           // per-group record arena
#define FILLB  ((EDGES + 255) / 256)            // 3125 (pass A)
#define PREPB  ((6 * HID * HID + 255) / 256)    // 384
#define CONVB  ((NODES * 64 + 255) / 256)       // 12500
#define FPB2   98                               // fill2 blocks per group

// ---------------------------------------------------------------------------
// Fused setup: pass-A edge compaction | weight prep | x->bf16.
// Pass A: per-block LDS histogram over 8 dst-groups, one global atomic per
// group per block, then coalesced packed (d_rel<<16|src) writes into
// per-group arenas. No wasted lanes, no random 2B scatter.
// ---------------------------------------------------------------------------
__global__ __launch_bounds__(256) void setup_kernel(
    const int* __restrict__ src, const int* __restrict__ dst,
    unsigned* __restrict__ ep, int* __restrict__ gcnt,
    const float* __restrict__ w1, const float* __restrict__ w2,
    unsigned short* __restrict__ wt,
    const float* __restrict__ x, unsigned* __restrict__ xb)
{
    const int b = blockIdx.x;
    if (b < FILLB) {
        __shared__ int lcnt[FGRPS], lbase[FGRPS];
        const int tid = threadIdx.x;
        int e = b * 256 + tid;
        if (tid < FGRPS) lcnt[tid] = 0;
        __syncthreads();
        int d = 0, s = 0, grp = 0, lpos = 0;
        bool ok = e < EDGES;
        if (ok) {
            d = dst[e]; s = src[e];
            grp = d / GSZ;
            lpos = atomicAdd(&lcnt[grp], 1);
        }
        __syncthreads();
        if (tid < FGRPS) lbase[tid] = atomicAdd(&gcnt[tid], lcnt[tid]);
        __syncthreads();
        if (ok) {
            int pos = lbase[grp] + lpos;
            if (pos < GCAP)
                ep[(size_t)grp * GCAP + pos] =
                    ((unsigned)(d - grp * GSZ) << 16) | (unsigned)s;
        }
    } else if (b < FILLB + PREPB) {
        int idx = (b - FILLB) * 256 + threadIdx.x;
        if (idx < 6 * HID * HID) {
            int m = idx >> 14;
            int n = (idx >> 7) & 127;
            int k = idx & 127;
            const float* w = (m < 3) ? (w1 + (size_t)m * HID * HID)
                                     : (w2 + (size_t)(m - 3) * HID * HID);
            wt[idx] = f2bf(w[(size_t)k * HID + n]);
        }
    } else {
        int i = (b - FILLB - PREPB) * 256 + threadIdx.x;   // f32 pair index
        if (i < NODES * 64) {
            float2 v = reinterpret_cast<const float2*>(x)[i];
            xb[i] = ((unsigned)f2bf(v.y) << 16) | f2bf(v.x);
        }
    }
}

// ---------------------------------------------------------------------------
// Pass B: group g (= blockIdx&7 -> XCD affinity) streams its compact record
// slice; deg/ell lines for its node range stay in ONE XCD's L2.
// ---------------------------------------------------------------------------
__global__ __launch_bounds__(256) void fill2_kernel(
    const unsigned* __restrict__ ep, const int* __restrict__ gcnt,
    int* __restrict__ deg, unsigned short* __restrict__ ell)
{
    const int grp = blockIdx.x & 7;
    const int bi  = blockIdx.x >> 3;          // 0..FPB2-1
    const int n0  = grp * GSZ;
    const int cnt = min(gcnt[grp], GCAP);
    const unsigned* p = ep + (size_t)grp * GCAP;
    for (int e = bi * 256 + threadIdx.x; e < cnt; e += FPB2 * 256) {
        unsigned r = p[e];
        int d = n0 + (int)(r >> 16);
        int s = (int)(r & 0xffffu);
        int pos = atomicAdd(&deg[d], 1);
        if (pos < ELLCAP) ell[(size_t)pos * NODES + d] = (unsigned short)s;
    }
}

// ---------------------------------------------------------------------------
// Fused GIN layer, 32-row tile, 512 threads (8 waves)  [round-12 structure]:
//   phase 0: stage deg[32] + ELL indices into LDS (coalesced, 64B/slot).
//   gather:  wave w gathers rows w*4..w*4+3 (quarter-wave per neighbor,
//            16 edges in flight); indices from LDS (single-hop chain).
//   GEMM:    wave w computes row-group (w>>2)*16 x col-quarter (w&3)*32.
// Barrier between GEMM1 A-frag loads and h1 write-back (rows shared by 4
// waves -- round-10 race).
// ---------------------------------------------------------------------------
__global__ __launch_bounds__(512) void layer_kernel(
    const unsigned short* __restrict__ X,
    const int* __restrict__ deg, const unsigned short* __restrict__ ell,
    const unsigned short* __restrict__ Wt1, const float* __restrict__ bias1,
    const unsigned short* __restrict__ Wt2, const float* __restrict__ bias2,
    unsigned short* __restrict__ C)
{
    __shared__ unsigned short As[32][136];
    __shared__ unsigned short idx_s[ELLCAP][32];
    __shared__ int deg_s[32];
    const int tid  = threadIdx.x;
    const int w    = tid >> 6;
    const int lane = tid & 63;
    const int q    = lane >> 4;
    const int lr   = lane & 15;
    const int row0 = blockIdx.x * 32;

    const uint4* xr = reinterpret_cast<const uint4*>(X);

    if (tid < 32) {
        int n = row0 + tid;
        if (n >= NODES) n = NODES - 1;
        deg_s[tid] = min(deg[n], ELLCAP);
    }
    __syncthreads();

    int maxd = 0;
    #pragma unroll
    for (int i = 0; i < 32; ++i) maxd = max(maxd, deg_s[i]);

    {
        const int sl0 = tid >> 5;
        const int nn  = tid & 31;
        int gn = row0 + nn;
        if (gn >= NODES) gn = NODES - 1;
        for (int s = sl0; s < maxd; s += 16)
            idx_s[s][nn] = ell[(size_t)s * NODES + gn];
    }
    __syncthreads();

    for (int i = 0; i < 4; ++i) {
        const int row = w * 4 + i;
        int n = row0 + row;
        if (n >= NODES) n = NODES - 1;

        float acc[8];
        #pragma unroll
        for (int k = 0; k < 8; ++k) acc[k] = 0.f;

        const int dg = deg_s[row];
        for (int e0 = 0; e0 < dg; e0 += 16) {
            uint4 v[4];
            unsigned m[4];
            #pragma unroll
            for (int j = 0; j < 4; ++j) {
                int e = e0 + 4 * j + q;
                bool ok = e < dg;
                m[j] = ok ? 0xffffffffu : 0u;
                int ec = ok ? e : 0;
                int s = idx_s[ec][row];
                v[j] = xr[(size_t)s * 16 + lr];
            }
            #pragma unroll
            for (int j = 0; j < 4; ++j) {
                const unsigned uu[4] = {v[j].x, v[j].y, v[j].z, v[j].w};
                #pragma unroll
                for (int k2 = 0; k2 < 4; ++k2) {
                    unsigned uv = uu[k2] & m[j];
                    acc[2 * k2]     += __uint_as_float(uv << 16);
                    acc[2 * k2 + 1] += __uint_as_float(uv & 0xffff0000u);
                }
            }
        }

        #pragma unroll
        for (int k = 0; k < 8; ++k) {
            acc[k] += __shfl_xor(acc[k], 16, 64);
            acc[k] += __shfl_xor(acc[k], 32, 64);
        }

        if (q == 0) {
            uint4 self = xr[(size_t)n * 16 + lr];
            const unsigned su[4] = {self.x, self.y, self.z, self.w};
            uint4 o;
            unsigned* ou = &o.x;
            #pragma unroll
            for (int j = 0; j < 4; ++j) {
                float c0 = acc[2 * j]     + __uint_as_float(su[j] << 16);
                float c1 = acc[2 * j + 1] + __uint_as_float(su[j] & 0xffff0000u);
                ou[j] = ((unsigned)f2bf(c1) << 16) | f2bf(c0);
            }
            *reinterpret_cast<uint4*>(&As[row][lr * 8]) = o;
        }
    }
    __syncthreads();

    const int rg = w >> 2;
    const int cq = w & 3;
    const int ar = rg * 16 + lr;

    bf16x8 af[4];
    f32x4 acc[2];

    // ---- GEMM 1 ----
    #pragma unroll
    for (int s = 0; s < 4; ++s)
        af[s] = *reinterpret_cast<const bf16x8*>(&As[ar][s * 32 + q * 8]);
    __syncthreads();   // all waves done READING As before any h1 write-back

    #pragma unroll
    for (int nt = 0; nt < 2; ++nt) acc[nt] = (f32x4){0.f, 0.f, 0.f, 0.f};
    {
        #pragma unroll
        for (int nt = 0; nt < 2; ++nt) {
            const unsigned short* wn = Wt1 + (size_t)(cq * 32 + nt * 16 + lr) * HID + q * 8;
            #pragma unroll
            for (int s = 0; s < 4; ++s) {
                bf16x8 b = *reinterpret_cast<const bf16x8*>(wn + s * 32);
                acc[nt] = __builtin_amdgcn_mfma_f32_16x16x32_bf16(b, af[s], acc[nt], 0, 0, 0);
            }
        }
    }

    {
        const float4* b4p = reinterpret_cast<const float4*>(bias1);
        #pragma unroll
        for (int nt = 0; nt < 2; ++nt) {
            int col = cq * 32 + nt * 16 + q * 4;
            float4 b4 = b4p[col >> 2];
            ushort4 o;
            o.x = f2bf(fmaxf(acc[nt][0] + b4.x, 0.f));
            o.y = f2bf(fmaxf(acc[nt][1] + b4.y, 0.f));
            o.z = f2bf(fmaxf(acc[nt][2] + b4.z, 0.f));
            o.w = f2bf(fmaxf(acc[nt][3] + b4.w, 0.f));
            *reinterpret_cast<ushort4*>(&As[ar][col]) = o;
        }
    }
    __syncthreads();

    // ---- GEMM 2 ----
    #pragma unroll
    for (int s = 0; s < 4; ++s)
        af[s] = *reinterpret_cast<const bf16x8*>(&As[ar][s * 32 + q * 8]);
    #pragma unroll
    for (int nt = 0; nt < 2; ++nt) acc[nt] = (f32x4){0.f, 0.f, 0.f, 0.f};
    {
        #pragma unroll
        for (int nt = 0; nt < 2; ++nt) {
            const unsigned short* wn = Wt2 + (size_t)(cq * 32 + nt * 16 + lr) * HID + q * 8;
            #pragma unroll
            for (int s = 0; s < 4; ++s) {
                bf16x8 b = *reinterpret_cast<const bf16x8*>(wn + s * 32);
                acc[nt] = __builtin_amdgcn_mfma_f32_16x16x32_bf16(b, af[s], acc[nt], 0, 0, 0);
            }
        }
    }

    const int row = row0 + ar;
    if (row < NODES) {
        const float4* b4p = reinterpret_cast<const float4*>(bias2);
        #pragma unroll
        for (int nt = 0; nt < 2; ++nt) {
            int col = cq * 32 + nt * 16 + q * 4;
            float4 b4 = b4p[col >> 2];
            ushort4 o;
            o.x = f2bf(fmaxf(acc[nt][0] + b4.x, 0.f));
            o.y = f2bf(fmaxf(acc[nt][1] + b4.y, 0.f));
            o.z = f2bf(fmaxf(acc[nt][2] + b4.z, 0.f));
            o.w = f2bf(fmaxf(acc[nt][3] + b4.w, 0.f));
            *reinterpret_cast<ushort4*>(C + (size_t)row * HID + col) = o;
        }
    }
}

// ---------------------------------------------------------------------------
// Fused tail: pool (sorted batch) -> MLP1 (relu) -> final GEMM, one block
// per graph. g and gh live in LDS; mw1/mw2 are L2-hot across 500 blocks.
// ---------------------------------------------------------------------------
__device__ __forceinline__ int lbound(const int* __restrict__ a, int v)
{
    int lo = 0, hi = NODES;
    while (lo < hi) {
        int m = (lo + hi) >> 1;
        if (a[m] < v) lo = m + 1; else hi = m;
    }
    return lo;
}

__global__ __launch_bounds__(256) void pool_mlp_kernel(
    const unsigned short* __restrict__ x,
    const int* __restrict__ batch,
    const float* __restrict__ mw1, const float* __restrict__ mb1,
    const float* __restrict__ mw2, const float* __restrict__ mb2,
    float* __restrict__ out)
{
    const int gid = blockIdx.x;
    const int beg = lbound(batch, gid);
    const int end = lbound(batch, gid + 1);

    const int c    = threadIdx.x & 127;
    const int half = threadIdx.x >> 7;

    float acc = 0.f;
    for (int r = beg + half; r < end; r += 2)
        acc += bf2f(x[(size_t)r * HID + c]);

    __shared__ float lds[256];
    __shared__ float gl[128];
    __shared__ float gh[128];
    lds[threadIdx.x] = acc;
    __syncthreads();
    if (threadIdx.x < 128)
        gl[threadIdx.x] = lds[threadIdx.x] + lds[threadIdx.x + 128];
    __syncthreads();

    if (threadIdx.x < 128) {
        float a = mb1[threadIdx.x];
        #pragma unroll 8
        for (int k = 0; k < 128; ++k)
            a += gl[k] * mw1[(size_t)k * HID + threadIdx.x];
        gh[threadIdx.x] = fmaxf(a, 0.f);
    }
    __syncthreads();

    if (threadIdx.x < OUTC) {
        float a = mb2[threadIdx.x];
        #pragma unroll 8
        for (int k = 0; k < 128; ++k)
            a += gh[k] * mw2[(size_t)k * OUTC + threadIdx.x];
        out[(size_t)gid * OUTC + threadIdx.x] = a;
    }
}

// ---------------------------------------------------------------------------
extern "C" void kernel_launch(void* const* d_in, const int* in_sizes, int n_in,
                              void* d_out, int out_size, void* d_ws, size_t ws_size,
                              hipStream_t stream)
{
    const float* x    = (const float*)d_in[0];
    const float* w1   = (const float*)d_in[1];
    const float* b1   = (const float*)d_in[2];
    const float* w2   = (const float*)d_in[3];
    const float* b2   = (const float*)d_in[4];
    const float* mw1  = (const float*)d_in[5];
    const float* mb1  = (const float*)d_in[6];
    const float* mw2  = (const float*)d_in[7];
    const float* mb2  = (const float*)d_in[8];
    const int*   ei   = (const int*)d_in[9];
    const int*   batch= (const int*)d_in[10];
    float* out = (float*)d_out;

    // workspace layout
    char* p = (char*)d_ws;
    unsigned short* buf0 = (unsigned short*)p;  p += (size_t)NODES * HID * 2;
    unsigned short* buf1 = (unsigned short*)p;  p += (size_t)NODES * HID * 2;
    unsigned short* ell  = (unsigned short*)p;  p += (size_t)NODES * ELLCAP * 2;
    unsigned short* wt   = (unsigned short*)p;  p += (size_t)6 * HID * HID * 2;
    unsigned* ep  = (unsigned*)p;               p += (size_t)FGRPS * GCAP * 4;
    int*   deg    = (int*)p;                    p += (size_t)NODES * 4;
    int*   gcnt   = (int*)p;                    p += FGRPS * 4;

    const int* src = ei;
    const int* dst = ei + EDGES;

    const int layerBlocks = (NODES + 31) / 32;          // 1563
    const int setupBlocks = FILLB + PREPB + CONVB;      // 16009

    // ---- setup: pass-A compaction + weight prep + x->bf16; then pass-B ----
    hipMemsetAsync(deg, 0, ((size_t)NODES + FGRPS) * sizeof(int), stream);
    setup_kernel<<<setupBlocks, 256, 0, stream>>>(
        src, dst, ep, gcnt, w1, w2, wt, x, (unsigned*)buf0);
    fill2_kernel<<<FGRPS * FPB2, 256, 0, stream>>>(ep, gcnt, deg, ell);

    // ---- 3 fused GIN layers (gather + dual GEMM), ping-pong buf0/buf1 ----
    unsigned short* bin  = buf0;
    unsigned short* bout = buf1;
    for (int l = 0; l < NLAYERS; ++l) {
        layer_kernel<<<layerBlocks, 512, 0, stream>>>(
            bin, deg, ell,
            wt + (size_t)l * HID * HID,       b1 + (size_t)l * HID,
            wt + (size_t)(l + 3) * HID * HID, b2 + (size_t)l * HID,
            bout);
        unsigned short* t = bin; bin = bout; bout = t;
    }

    // ---- fused pool + MLP + final ----
    pool_mlp_kernel<<<GRAPHS, 256, 0, stream>>>(bin, batch, mw1, mb1, mw2, mb2, out);
}

// Round 17
// 236.374 us; speedup vs baseline: 1.1667x; 1.1667x over previous
//
#include <hip/hip_runtime.h>

#define NODES   50000
#define EDGES   800000
#define GRAPHS  500
#define HID     128
#define OUTC    10
#define NLAYERS 3
#define ELLCAP  64

typedef __bf16 bf16x8 __attribute__((ext_vector_type(8)));
typedef float  f32x4  __attribute__((ext_vector_type(4)));

__device__ __forceinline__ unsigned short f2bf(float f){
    unsigned u = __float_as_uint(f);
    u = (u + 0x7fffu + ((u >> 16) & 1u)) >> 16;
    return (unsigned short)u;
}
__device__ __forceinline__ float bf2f(unsigned short h){
    return __uint_as_float(((unsigned)h) << 16);
}

#define FGRPS  8                                // XCD groups
#define FPB    392                              // fill blocks per group
#define FILLB  (FGRPS * FPB)                    // 3136
#define GSZ    (NODES / FGRPS)                  // 6250 nodes per group
#define PREPB  ((6 * HID * HID + 255) / 256)    // 384
#define CONVB  ((NODES * 64 + 255) / 256)       // 12500

// ---------------------------------------------------------------------------
// Fused setup: XCD-partitioned transposed-ELL fill | weight prep | x->bf16.
// Fill: group g (= blockIdx&7, round-robins onto XCDs) scans ALL edges but
// commits only dst in [g*GSZ,(g+1)*GSZ) -> deg/ell lines for a node range
// stay in ONE XCD's L2. Edge-list reads are 8x but L3-cached.
// (Round-16's compacted 2-pass variant regressed: LDS-atomic histogram
// serialization + ep round-trip cost more than the locality it bought.)
// ---------------------------------------------------------------------------
__global__ __launch_bounds__(256) void setup_kernel(
    const int* __restrict__ src, const int* __restrict__ dst,
    int* __restrict__ deg, unsigned short* __restrict__ ell,
    const float* __restrict__ w1, const float* __restrict__ w2,
    unsigned short* __restrict__ wt,
    const float* __restrict__ x, unsigned* __restrict__ xb)
{
    const int b = blockIdx.x;
    if (b < FILLB) {
        const int grp = b & 7;
        const int bi  = b >> 3;
        const int lo  = grp * GSZ;
        const int hi  = lo + GSZ;
        for (int e = bi * 256 + threadIdx.x; e < EDGES; e += FPB * 256) {
            int d = dst[e];
            if (d >= lo && d < hi) {
                int pos = atomicAdd(&deg[d], 1);
                if (pos < ELLCAP)
                    ell[(size_t)pos * NODES + d] = (unsigned short)src[e];
            }
        }
    } else if (b < FILLB + PREPB) {
        int idx = (b - FILLB) * 256 + threadIdx.x;
        if (idx < 6 * HID * HID) {
            int m = idx >> 14;
            int n = (idx >> 7) & 127;
            int k = idx & 127;
            const float* w = (m < 3) ? (w1 + (size_t)m * HID * HID)
                                     : (w2 + (size_t)(m - 3) * HID * HID);
            wt[idx] = f2bf(w[(size_t)k * HID + n]);
        }
    } else {
        int i = (b - FILLB - PREPB) * 256 + threadIdx.x;   // f32 pair index
        if (i < NODES * 64) {
            float2 v = reinterpret_cast<const float2*>(x)[i];
            xb[i] = ((unsigned)f2bf(v.y) << 16) | f2bf(v.x);
        }
    }
}

// ---------------------------------------------------------------------------
// Fused GIN layer, 32-row tile, 512 threads (8 waves)  [round-12 structure]:
//   phase 0: stage deg[32] + ELL indices into LDS (coalesced, 64B/slot).
//   gather:  wave w gathers rows w*4..w*4+3 (quarter-wave per neighbor,
//            16 edges in flight); indices from LDS (single-hop chain).
//   GEMM:    wave w computes row-group (w>>2)*16 x col-quarter (w&3)*32.
// Barrier between GEMM1 A-frag loads and h1 write-back (rows shared by 4
// waves -- round-10 race).
// ---------------------------------------------------------------------------
__global__ __launch_bounds__(512) void layer_kernel(
    const unsigned short* __restrict__ X,
    const int* __restrict__ deg, const unsigned short* __restrict__ ell,
    const unsigned short* __restrict__ Wt1, const float* __restrict__ bias1,
    const unsigned short* __restrict__ Wt2, const float* __restrict__ bias2,
    unsigned short* __restrict__ C)
{
    __shared__ unsigned short As[32][136];
    __shared__ unsigned short idx_s[ELLCAP][32];
    __shared__ int deg_s[32];
    const int tid  = threadIdx.x;
    const int w    = tid >> 6;
    const int lane = tid & 63;
    const int q    = lane >> 4;
    const int lr   = lane & 15;
    const int row0 = blockIdx.x * 32;

    const uint4* xr = reinterpret_cast<const uint4*>(X);

    if (tid < 32) {
        int n = row0 + tid;
        if (n >= NODES) n = NODES - 1;
        deg_s[tid] = min(deg[n], ELLCAP);
    }
    __syncthreads();

    int maxd = 0;
    #pragma unroll
    for (int i = 0; i < 32; ++i) maxd = max(maxd, deg_s[i]);

    {
        const int sl0 = tid >> 5;
        const int nn  = tid & 31;
        int gn = row0 + nn;
        if (gn >= NODES) gn = NODES - 1;
        for (int s = sl0; s < maxd; s += 16)
            idx_s[s][nn] = ell[(size_t)s * NODES + gn];
    }
    __syncthreads();

    for (int i = 0; i < 4; ++i) {
        const int row = w * 4 + i;
        int n = row0 + row;
        if (n >= NODES) n = NODES - 1;

        float acc[8];
        #pragma unroll
        for (int k = 0; k < 8; ++k) acc[k] = 0.f;

        const int dg = deg_s[row];
        for (int e0 = 0; e0 < dg; e0 += 16) {
            uint4 v[4];
            unsigned m[4];
            #pragma unroll
            for (int j = 0; j < 4; ++j) {
                int e = e0 + 4 * j + q;
                bool ok = e < dg;
                m[j] = ok ? 0xffffffffu : 0u;
                int ec = ok ? e : 0;
                int s = idx_s[ec][row];
                v[j] = xr[(size_t)s * 16 + lr];
            }
            #pragma unroll
            for (int j = 0; j < 4; ++j) {
                const unsigned uu[4] = {v[j].x, v[j].y, v[j].z, v[j].w};
                #pragma unroll
                for (int k2 = 0; k2 < 4; ++k2) {
                    unsigned uv = uu[k2] & m[j];
                    acc[2 * k2]     += __uint_as_float(uv << 16);
                    acc[2 * k2 + 1] += __uint_as_float(uv & 0xffff0000u);
                }
            }
        }

        #pragma unroll
        for (int k = 0; k < 8; ++k) {
            acc[k] += __shfl_xor(acc[k], 16, 64);
            acc[k] += __shfl_xor(acc[k], 32, 64);
        }

        if (q == 0) {
            uint4 self = xr[(size_t)n * 16 + lr];
            const unsigned su[4] = {self.x, self.y, self.z, self.w};
            uint4 o;
            unsigned* ou = &o.x;
            #pragma unroll
            for (int j = 0; j < 4; ++j) {
                float c0 = acc[2 * j]     + __uint_as_float(su[j] << 16);
                float c1 = acc[2 * j + 1] + __uint_as_float(su[j] & 0xffff0000u);
                ou[j] = ((unsigned)f2bf(c1) << 16) | f2bf(c0);
            }
            *reinterpret_cast<uint4*>(&As[row][lr * 8]) = o;
        }
    }
    __syncthreads();

    const int rg = w >> 2;
    const int cq = w & 3;
    const int ar = rg * 16 + lr;

    bf16x8 af[4];
    f32x4 acc[2];

    // ---- GEMM 1 ----
    #pragma unroll
    for (int s = 0; s < 4; ++s)
        af[s] = *reinterpret_cast<const bf16x8*>(&As[ar][s * 32 + q * 8]);
    __syncthreads();   // all waves done READING As before any h1 write-back

    #pragma unroll
    for (int nt = 0; nt < 2; ++nt) acc[nt] = (f32x4){0.f, 0.f, 0.f, 0.f};
    {
        #pragma unroll
        for (int nt = 0; nt < 2; ++nt) {
            const unsigned short* wn = Wt1 + (size_t)(cq * 32 + nt * 16 + lr) * HID + q * 8;
            #pragma unroll
            for (int s = 0; s < 4; ++s) {
                bf16x8 b = *reinterpret_cast<const bf16x8*>(wn + s * 32);
                acc[nt] = __builtin_amdgcn_mfma_f32_16x16x32_bf16(b, af[s], acc[nt], 0, 0, 0);
            }
        }
    }

    {
        const float4* b4p = reinterpret_cast<const float4*>(bias1);
        #pragma unroll
        for (int nt = 0; nt < 2; ++nt) {
            int col = cq * 32 + nt * 16 + q * 4;
            float4 b4 = b4p[col >> 2];
            ushort4 o;
            o.x = f2bf(fmaxf(acc[nt][0] + b4.x, 0.f));
            o.y = f2bf(fmaxf(acc[nt][1] + b4.y, 0.f));
            o.z = f2bf(fmaxf(acc[nt][2] + b4.z, 0.f));
            o.w = f2bf(fmaxf(acc[nt][3] + b4.w, 0.f));
            *reinterpret_cast<ushort4*>(&As[ar][col]) = o;
        }
    }
    __syncthreads();

    // ---- GEMM 2 ----
    #pragma unroll
    for (int s = 0; s < 4; ++s)
        af[s] = *reinterpret_cast<const bf16x8*>(&As[ar][s * 32 + q * 8]);
    #pragma unroll
    for (int nt = 0; nt < 2; ++nt) acc[nt] = (f32x4){0.f, 0.f, 0.f, 0.f};
    {
        #pragma unroll
        for (int nt = 0; nt < 2; ++nt) {
            const unsigned short* wn = Wt2 + (size_t)(cq * 32 + nt * 16 + lr) * HID + q * 8;
            #pragma unroll
            for (int s = 0; s < 4; ++s) {
                bf16x8 b = *reinterpret_cast<const bf16x8*>(wn + s * 32);
                acc[nt] = __builtin_amdgcn_mfma_f32_16x16x32_bf16(b, af[s], acc[nt], 0, 0, 0);
            }
        }
    }

    const int row = row0 + ar;
    if (row < NODES) {
        const float4* b4p = reinterpret_cast<const float4*>(bias2);
        #pragma unroll
        for (int nt = 0; nt < 2; ++nt) {
            int col = cq * 32 + nt * 16 + q * 4;
            float4 b4 = b4p[col >> 2];
            ushort4 o;
            o.x = f2bf(fmaxf(acc[nt][0] + b4.x, 0.f));
            o.y = f2bf(fmaxf(acc[nt][1] + b4.y, 0.f));
            o.z = f2bf(fmaxf(acc[nt][2] + b4.z, 0.f));
            o.w = f2bf(fmaxf(acc[nt][3] + b4.w, 0.f));
            *reinterpret_cast<ushort4*>(C + (size_t)row * HID + col) = o;
        }
    }
}

// ---------------------------------------------------------------------------
// Fused tail: pool (sorted batch) -> MLP1 (relu) -> final GEMM, one block
// per graph. g and gh live in LDS; mw1/mw2 are L2-hot across 500 blocks.
// ---------------------------------------------------------------------------
__device__ __forceinline__ int lbound(const int* __restrict__ a, int v)
{
    int lo = 0, hi = NODES;
    while (lo < hi) {
        int m = (lo + hi) >> 1;
        if (a[m] < v) lo = m + 1; else hi = m;
    }
    return lo;
}

__global__ __launch_bounds__(256) void pool_mlp_kernel(
    const unsigned short* __restrict__ x,
    const int* __restrict__ batch,
    const float* __restrict__ mw1, const float* __restrict__ mb1,
    const float* __restrict__ mw2, const float* __restrict__ mb2,
    float* __restrict__ out)
{
    const int gid = blockIdx.x;
    const int beg = lbound(batch, gid);
    const int end = lbound(batch, gid + 1);

    const int c    = threadIdx.x & 127;
    const int half = threadIdx.x >> 7;

    float acc = 0.f;
    for (int r = beg + half; r < end; r += 2)
        acc += bf2f(x[(size_t)r * HID + c]);

    __shared__ float lds[256];
    __shared__ float gl[128];
    __shared__ float gh[128];
    lds[threadIdx.x] = acc;
    __syncthreads();
    if (threadIdx.x < 128)
        gl[threadIdx.x] = lds[threadIdx.x] + lds[threadIdx.x + 128];
    __syncthreads();

    if (threadIdx.x < 128) {
        float a = mb1[threadIdx.x];
        #pragma unroll 8
        for (int k = 0; k < 128; ++k)
            a += gl[k] * mw1[(size_t)k * HID + threadIdx.x];
        gh[threadIdx.x] = fmaxf(a, 0.f);
    }
    __syncthreads();

    if (threadIdx.x < OUTC) {
        float a = mb2[threadIdx.x];
        #pragma unroll 8
        for (int k = 0; k < 128; ++k)
            a += gh[k] * mw2[(size_t)k * OUTC + threadIdx.x];
        out[(size_t)gid * OUTC + threadIdx.x] = a;
    }
}

// ---------------------------------------------------------------------------
extern "C" void kernel_launch(void* const* d_in, const int* in_sizes, int n_in,
                              void* d_out, int out_size, void* d_ws, size_t ws_size,
                              hipStream_t stream)
{
    const float* x    = (const float*)d_in[0];
    const float* w1   = (const float*)d_in[1];
    const float* b1   = (const float*)d_in[2];
    const float* w2   = (const float*)d_in[3];
    const float* b2   = (const float*)d_in[4];
    const float* mw1  = (const float*)d_in[5];
    const float* mb1  = (const float*)d_in[6];
    const float* mw2  = (const float*)d_in[7];
    const float* mb2  = (const float*)d_in[8];
    const int*   ei   = (const int*)d_in[9];
    const int*   batch= (const int*)d_in[10];
    float* out = (float*)d_out;

    // workspace layout
    char* p = (char*)d_ws;
    unsigned short* buf0 = (unsigned short*)p;  p += (size_t)NODES * HID * 2;
    unsigned short* buf1 = (unsigned short*)p;  p += (size_t)NODES * HID * 2;
    unsigned short* ell  = (unsigned short*)p;  p += (size_t)NODES * ELLCAP * 2;
    unsigned short* wt   = (unsigned short*)p;  p += (size_t)6 * HID * HID * 2;
    int*   deg    = (int*)p;                    p += (size_t)NODES * 4;

    const int* src = ei;
    const int* dst = ei + EDGES;

    const int layerBlocks = (NODES + 31) / 32;          // 1563
    const int setupBlocks = FILLB + PREPB + CONVB;      // 16020

    // ---- setup: XCD-partitioned ELL fill + weight prep + x->bf16 ----
    hipMemsetAsync(deg, 0, (size_t)NODES * sizeof(int), stream);
    setup_kernel<<<setupBlocks, 256, 0, stream>>>(
        src, dst, deg, ell, w1, w2, wt, x, (unsigned*)buf0);

    // ---- 3 fused GIN layers (gather + dual GEMM), ping-pong buf0/buf1 ----
    unsigned short* bin  = buf0;
    unsigned short* bout = buf1;
    for (int l = 0; l < NLAYERS; ++l) {
        layer_kernel<<<layerBlocks, 512, 0, stream>>>(
            bin, deg, ell,
            wt + (size_t)l * HID * HID,       b1 + (size_t)l * HID,
            wt + (size_t)(l + 3) * HID * HID, b2 + (size_t)l * HID,
            bout);
        unsigned short* t = bin; bin = bout; bout = t;
    }

    // ---- fused pool + MLP + final ----
    pool_mlp_kernel<<<GRAPHS, 256, 0, stream>>>(bin, batch, mw1, mb1, mw2, mb2, out);
}